// Round 2
// baseline (11027.158 us; speedup 1.0000x reference)
//
#include <hip/hip_runtime.h>
#include <hip/hip_cooperative_groups.h>

// TerminalGRU: B=256 T=256 D=512 H=1024 C=128
// Chunked pipeline (TC=32 steps x 8 chunks), peak ws ~85MB:
//   prep: bf16 weight conversions + prev-id extraction (once)
//   per chunk: k_cvtx (X chunk -> bf16) -> k_gates (8192x3072x512 MFMA GEMM)
//              -> k_scan coop (32 steps, W_hh VGPR-resident, grid.sync per step)
//              -> k_logits (8192x128x1024 -> d_out)

#define DEVI __device__ __forceinline__

typedef __bf16 bf16x8 __attribute__((ext_vector_type(8)));
typedef float f32x4 __attribute__((ext_vector_type(4)));

static constexpr int Bb = 256, Tt = 256, Dd = 512, Hh = 1024, Cc = 128;
static constexpr int G3 = 3072, DC = 640, TC = 32, NC = Tt / TC;

DEVI unsigned short f2b(float f) {
  union { float f; unsigned u; } v; v.f = f;
  unsigned r = v.u + 0x7FFFu + ((v.u >> 16) & 1u);
  return (unsigned short)(r >> 16);
}
DEVI float b2f(unsigned short h) {
  union { unsigned u; float f; } v; v.u = ((unsigned)h) << 16; return v.f;
}

// ---------------- prep kernels ----------------

// contiguous f32 -> bf16, 8 elems/thread
__global__ __launch_bounds__(256) void k_cvt(const float* __restrict__ x,
                                             unsigned short* __restrict__ o, int n) {
  int i = (blockIdx.x * 256 + threadIdx.x) * 8;
  if (i >= n) return;
  float4 a = *(const float4*)(x + i), b = *(const float4*)(x + i + 4);
  uint4 u;
  u.x = (unsigned)f2b(a.x) | ((unsigned)f2b(a.y) << 16);
  u.y = (unsigned)f2b(a.z) | ((unsigned)f2b(a.w) << 16);
  u.z = (unsigned)f2b(b.x) | ((unsigned)f2b(b.y) << 16);
  u.w = (unsigned)f2b(b.z) | ((unsigned)f2b(b.w) << 16);
  *(uint4*)(o + i) = u;
}

// W_ih[:, :512] -> bf16 [3072][512]
__global__ __launch_bounds__(256) void k_cvt_wa(const float* __restrict__ Wih,
                                                unsigned short* __restrict__ Wa) {
  int u = blockIdx.x * 256 + threadIdx.x;   // 3072*64 units
  int g = u >> 6, d = (u & 63) * 8;
  const float* p = Wih + (size_t)g * DC + d;
  float4 a = *(const float4*)p, b = *(const float4*)(p + 4);
  uint4 o;
  o.x = (unsigned)f2b(a.x) | ((unsigned)f2b(a.y) << 16);
  o.y = (unsigned)f2b(a.z) | ((unsigned)f2b(a.w) << 16);
  o.z = (unsigned)f2b(b.x) | ((unsigned)f2b(b.y) << 16);
  o.w = (unsigned)f2b(b.z) | ((unsigned)f2b(b.w) << 16);
  *(uint4*)(Wa + (size_t)g * Dd + d) = o;
}

// W_ih[:, 512:]^T -> bf16 [128][3072]
__global__ __launch_bounds__(256) void k_cvt_wct(const float* __restrict__ Wih,
                                                 unsigned short* __restrict__ WcT) {
  int g = blockIdx.x * 256 + threadIdx.x;  // 0..3071
  int c = blockIdx.y;                      // 0..127
  WcT[(size_t)c * G3 + g] = f2b(Wih[(size_t)g * DC + Dd + c]);
}

// prev-step one-hot index: pid[b*T+t] = argmax(true_seq[b,t-1]), -1 for t==0
__global__ __launch_bounds__(256) void k_pid(const float* __restrict__ ts,
                                             int* __restrict__ pid) {
  int bt = blockIdx.x * 256 + threadIdx.x;  // 65536
  int t = bt & (Tt - 1);
  if (t == 0) { pid[bt] = -1; return; }
  const float* p = ts + (size_t)(bt - 1) * Cc;
  int id = 0;
  for (int c = 0; c < Cc; c += 4) {
    float4 v = *(const float4*)(p + c);
    if (v.x > 0.5f) id = c;
    if (v.y > 0.5f) id = c + 1;
    if (v.z > 0.5f) id = c + 2;
    if (v.w > 0.5f) id = c + 3;
  }
  pid[bt] = id;
}

// X chunk -> bf16 chunk-local rows: Xc[(b*TC+tl)*Dd + d] = gru[b][t0+tl][d]
__global__ __launch_bounds__(256) void k_cvtx(const float* __restrict__ gru,
                                              unsigned short* __restrict__ Xc, int t0) {
  int u = (blockIdx.x * 256 + threadIdx.x) * 8;  // Bb*TC*Dd elems
  int m = u >> 9, d = u & 511;
  int b = m >> 5, tl = m & 31;
  const float* p = gru + ((size_t)(b * Tt + t0 + tl)) * Dd + d;
  float4 a = *(const float4*)p, c = *(const float4*)(p + 4);
  uint4 o;
  o.x = (unsigned)f2b(a.x) | ((unsigned)f2b(a.y) << 16);
  o.y = (unsigned)f2b(a.z) | ((unsigned)f2b(a.w) << 16);
  o.z = (unsigned)f2b(c.x) | ((unsigned)f2b(c.y) << 16);
  o.w = (unsigned)f2b(c.z) | ((unsigned)f2b(c.w) << 16);
  *(uint4*)(Xc + (size_t)m * Dd + d) = o;
}

// ---------------- gates GEMM (per chunk, M=8192) ----------------
__global__ __launch_bounds__(256) void k_gates(const unsigned short* __restrict__ Xc,
                                               const unsigned short* __restrict__ Wa,
                                               const unsigned short* __restrict__ WcT,
                                               const float* __restrict__ bih,
                                               const int* __restrict__ pid,
                                               unsigned short* __restrict__ gx, int t0) {
  int m0 = blockIdx.x * 128, n0 = blockIdx.y * 128;
  int l = threadIdx.x & 63, w = threadIdx.x >> 6;
  int wm = w >> 1, wn = w & 1;
  int r0 = m0 + 64 * wm, c0 = n0 + 64 * wn;
  int lr = l & 15, lk = (l >> 4) * 8;
  f32x4 acc[4][4] = {};
  for (int kk = 0; kk < 16; ++kk) {
    int k = kk * 32 + lk;
    bf16x8 a[4], b[4];
#pragma unroll
    for (int mf = 0; mf < 4; ++mf)
      a[mf] = *(const bf16x8*)(Xc + (size_t)(r0 + 16 * mf + lr) * Dd + k);
#pragma unroll
    for (int nf = 0; nf < 4; ++nf)
      b[nf] = *(const bf16x8*)(Wa + (size_t)(c0 + 16 * nf + lr) * Dd + k);
#pragma unroll
    for (int mf = 0; mf < 4; ++mf)
#pragma unroll
      for (int nf = 0; nf < 4; ++nf)
        acc[mf][nf] = __builtin_amdgcn_mfma_f32_16x16x32_bf16(a[mf], b[nf], acc[mf][nf], 0, 0, 0);
  }
  int ri = (l >> 4) * 4;
  for (int mf = 0; mf < 4; ++mf) {
    int rowb = r0 + 16 * mf + ri;
    int pd[4];
#pragma unroll
    for (int i = 0; i < 4; ++i) {
      int rr = rowb + i;
      pd[i] = pid[(size_t)(rr >> 5) * Tt + t0 + (rr & 31)];
    }
    for (int nf = 0; nf < 4; ++nf) {
      int g = c0 + 16 * nf + lr;
      float bi = bih[g];
#pragma unroll
      for (int i = 0; i < 4; ++i) {
        float v = acc[mf][nf][i] + bi;
        if (pd[i] >= 0) v += b2f(WcT[(size_t)pd[i] * G3 + g]);
        gx[(size_t)(rowb + i) * G3 + g] = f2b(v);
      }
    }
  }
}

// ---------------- recurrent scan chunk (cooperative) ----------------
// 256 blocks x 256 threads. XCD-aware: xcd=bid&7, slot=bid>>3, mg=xcd>>1,
// nb=slot*2+(xcd&1): each XCD hosts 32 col-blocks of ONE batch-group -> h reads L2-hit.
// Block: batch rows [64mg,64mg+64), hcols [16nb,16nb+16). Wave w K-slice [256w,256w+256).
// W_hh slice in VGPRs: Breg[3][8] = 96 VGPRs.
__global__ __launch_bounds__(256, 1) void k_scan(const unsigned short* __restrict__ Whh,
                                                 const float* __restrict__ bhh,
                                                 const unsigned short* __restrict__ gx,
                                                 unsigned short* __restrict__ hbuf,
                                                 unsigned short* __restrict__ hsc) {
  __shared__ float red[4 * 64 * 52];  // [wave][row64][col48 pad52] = 53KB
  int tid = threadIdx.x;
  int l = tid & 63, w = tid >> 6;
  int bid = blockIdx.x;
  int xcd = bid & 7, slot = bid >> 3;
  int mg = xcd >> 1, nb = slot * 2 + (xcd & 1);
  int lr = l & 15, lk = (l >> 4) * 8;
  int hcolBase = 16 * nb;

  bf16x8 Breg[3][8];
#pragma unroll
  for (int nf = 0; nf < 3; ++nf) {
    int g = nf * Hh + hcolBase + lr;
#pragma unroll
    for (int kk = 0; kk < 8; ++kk) {
      int k = 256 * w + 32 * kk + lk;
      Breg[nf][kk] = *(const bf16x8*)(Whh + (size_t)g * Hh + k);
    }
  }
  int j = lr;
  int hcol = hcolBase + j;
  float bhr = bhh[hcol], bhz = bhh[Hh + hcol], bhn = bhh[2 * Hh + hcol];
  int ri = (l >> 4) * 4;

  for (int tl = 0; tl < TC; ++tl) {
    const unsigned short* hcur = hbuf + (size_t)(tl & 1) * Bb * Hh;
    unsigned short* hnxt = hbuf + (size_t)((tl & 1) ^ 1) * Bb * Hh;
    f32x4 acc[4][3] = {};
#pragma unroll
    for (int kk = 0; kk < 8; ++kk) {
      int k = 256 * w + 32 * kk + lk;
      bf16x8 a[4];
#pragma unroll
      for (int mf = 0; mf < 4; ++mf)
        a[mf] = *(const bf16x8*)(hcur + (size_t)(64 * mg + 16 * mf + lr) * Hh + k);
#pragma unroll
      for (int mf = 0; mf < 4; ++mf)
#pragma unroll
        for (int nf = 0; nf < 3; ++nf)
          acc[mf][nf] = __builtin_amdgcn_mfma_f32_16x16x32_bf16(a[mf], Breg[nf][kk], acc[mf][nf], 0, 0, 0);
    }
#pragma unroll
    for (int mf = 0; mf < 4; ++mf)
#pragma unroll
      for (int nf = 0; nf < 3; ++nf)
#pragma unroll
        for (int i = 0; i < 4; ++i)
          red[(w * 64 + 16 * mf + ri + i) * 52 + 16 * nf + lr] = acc[mf][nf][i];
    __syncthreads();
#pragma unroll
    for (int ii = 0; ii < 4; ++ii) {
      int r = 16 * w + ri + ii;
      int b = 64 * mg + r;
      float sr = 0.f, sz = 0.f, sn = 0.f;
#pragma unroll
      for (int w2 = 0; w2 < 4; ++w2) {
        const float* rp = &red[(w2 * 64 + r) * 52];
        sr += rp[j];
        sz += rp[16 + j];
        sn += rp[32 + j];
      }
      size_t gxo = (size_t)(b * TC + tl) * G3;
      float xr = b2f(gx[gxo + hcol]);
      float xz = b2f(gx[gxo + Hh + hcol]);
      float xn = b2f(gx[gxo + 2 * Hh + hcol]);
      float hr = sr + bhr, hz = sz + bhz, hn = sn + bhn;
      float rg = 1.f / (1.f + __expf(-(xr + hr)));
      float zg = 1.f / (1.f + __expf(-(xz + hz)));
      float pre = xn + rg * hn;
      pre = fminf(fmaxf(pre, -15.f), 15.f);
      float e = __expf(-2.f * pre);
      float ng = (1.f - e) / (1.f + e);
      float hp = b2f(hcur[(size_t)b * Hh + hcol]);
      float hv = (1.f - zg) * ng + zg * hp;
      unsigned short h16 = f2b(hv);
      hnxt[(size_t)b * Hh + hcol] = h16;
      hsc[(size_t)(b * TC + tl) * Hh + hcol] = h16;
    }
    cooperative_groups::this_grid().sync();
  }
}

// ---------------- logits GEMM (per chunk, M=8192) ----------------
__global__ __launch_bounds__(256) void k_logits(const unsigned short* __restrict__ hsc,
                                                const unsigned short* __restrict__ Wo,
                                                const float* __restrict__ bout,
                                                float* __restrict__ out, int t0) {
  int blk = blockIdx.x;  // 128
  int l = threadIdx.x & 63, w = threadIdx.x >> 6;
  int lr = l & 15, lk = (l >> 4) * 8;
  int r0 = blk * 64 + 16 * w;
  f32x4 acc[8] = {};
  for (int kk = 0; kk < 32; ++kk) {
    int k = kk * 32 + lk;
    bf16x8 a = *(const bf16x8*)(hsc + (size_t)(r0 + lr) * Hh + k);
#pragma unroll
    for (int nf = 0; nf < 8; ++nf) {
      bf16x8 b = *(const bf16x8*)(Wo + (size_t)(16 * nf + lr) * Hh + k);
      acc[nf] = __builtin_amdgcn_mfma_f32_16x16x32_bf16(a, b, acc[nf], 0, 0, 0);
    }
  }
  int ri = (l >> 4) * 4;
  for (int nf = 0; nf < 8; ++nf) {
    int c = 16 * nf + lr;
    float bo = bout[c];
#pragma unroll
    for (int i = 0; i < 4; ++i) {
      int m = r0 + ri + i;  // chunk-local row
      int grow = (m >> 5) * Tt + t0 + (m & 31);
      out[(size_t)grow * Cc + c] = acc[nf][i] + bo;
    }
  }
}

// ---------------- launch ----------------
extern "C" void kernel_launch(void* const* d_in, const int* in_sizes, int n_in,
                              void* d_out, int out_size, void* d_ws, size_t ws_size,
                              hipStream_t stream) {
  const float* gru = (const float*)d_in[0];
  const float* ts  = (const float*)d_in[1];
  const float* Wih = (const float*)d_in[2];
  const float* bih = (const float*)d_in[3];
  const float* Whh = (const float*)d_in[4];
  const float* bhh = (const float*)d_in[5];
  const float* Wou = (const float*)d_in[6];
  const float* bou = (const float*)d_in[7];

  char* ws = (char*)d_ws;
  size_t off = 0;
  auto alloc = [&](size_t bytes) -> void* {
    void* p = ws + off;
    off += (bytes + 255) & ~(size_t)255;
    return p;
  };
  unsigned short* Wa  = (unsigned short*)alloc((size_t)G3 * Dd * 2);        // 3.1MB
  unsigned short* WcT = (unsigned short*)alloc((size_t)Cc * G3 * 2);        // 0.8MB
  unsigned short* Whb = (unsigned short*)alloc((size_t)G3 * Hh * 2);        // 6.3MB
  unsigned short* Wob = (unsigned short*)alloc((size_t)Cc * Hh * 2);        // 0.26MB
  int*            pid = (int*)alloc((size_t)Bb * Tt * 4);                   // 0.26MB
  unsigned short* hb  = (unsigned short*)alloc((size_t)2 * Bb * Hh * 2);    // 1MB
  unsigned short* Xc  = (unsigned short*)alloc((size_t)Bb * TC * Dd * 2);   // 8.4MB
  unsigned short* gx  = (unsigned short*)alloc((size_t)Bb * TC * G3 * 2);   // 50.3MB
  unsigned short* hsc = (unsigned short*)alloc((size_t)Bb * TC * Hh * 2);   // 16.8MB
  if (ws_size < off) return;  // clean fail (absmax = max|ref|) instead of OOB fault

  k_cvt<<<(G3 * Hh) / 2048, 256, 0, stream>>>(Whh, Whb, G3 * Hh);
  k_cvt<<<(Cc * Hh) / 2048, 256, 0, stream>>>(Wou, Wob, Cc * Hh);
  k_cvt_wa<<<(G3 * 64) / 256, 256, 0, stream>>>(Wih, Wa);
  k_cvt_wct<<<dim3(G3 / 256, Cc), 256, 0, stream>>>(Wih, WcT);
  k_pid<<<(Bb * Tt) / 256, 256, 0, stream>>>(ts, pid);
  hipMemsetAsync(hb, 0, (size_t)2 * Bb * Hh * 2, stream);

  for (int c = 0; c < NC; ++c) {
    int t0 = c * TC;
    k_cvtx<<<(Bb * TC * Dd) / 2048, 256, 0, stream>>>(gru, Xc, t0);
    k_gates<<<dim3((Bb * TC) / 128, G3 / 128), 256, 0, stream>>>(Xc, Wa, WcT, bih, pid, gx, t0);
    void* args[] = { (void*)&Whb, (void*)&bhh, (void*)&gx, (void*)&hb, (void*)&hsc };
    hipLaunchCooperativeKernel((const void*)k_scan, dim3(256), dim3(256), args, 0, stream);
    k_logits<<<(Bb * TC) / 64, 256, 0, stream>>>(hsc, Wob, bou, (float*)d_out, t0);
  }
}

// Round 5
// 6357.718 us; speedup vs baseline: 1.7345x; 1.7345x over previous
//
#include <hip/hip_runtime.h>

// TerminalGRU: B=256 T=256 D=512 H=1024 C=128
// Chunked pipeline (TC=32 steps x 8 chunks):
//   per chunk: k_cvtx -> k_gates (MFMA GEMM) -> k_scan (PLAIN launch, 256 blocks,
//              group-scoped release/acquire + MALL-coherent h exchange) -> k_logits
// Round-4 post-mortem: rounds 3/4 failed BIT-IDENTICALLY (absmax .7159 ~= logits
// = b_out only) across two different sync protocols => k_scan never ran; the
// hipLaunchCooperativeKernel call was failing, not the protocol. This round:
// plain launch (256 blocks <= 256 CUs, ~110 VGPR / 53KB LDS => all co-resident),
// round-2's proven compute structure, h exchanged via AGENT-scope atomics
// (executed at MALL -- no L1/L2 staleness), counters via RELEASE/ACQUIRE.

#define DEVI __device__ __forceinline__

typedef __bf16 bf16x8 __attribute__((ext_vector_type(8)));
typedef float f32x4 __attribute__((ext_vector_type(4)));
typedef unsigned long long u64;

static constexpr int Bb = 256, Tt = 256, Dd = 512, Hh = 1024, Cc = 128;
static constexpr int G3 = 3072, DC = 640, TC = 32, NC = Tt / TC;

DEVI unsigned short f2b(float f) {
  union { float f; unsigned u; } v; v.f = f;
  unsigned r = v.u + 0x7FFFu + ((v.u >> 16) & 1u);
  return (unsigned short)(r >> 16);
}
DEVI float b2f(unsigned short h) {
  union { unsigned u; float f; } v; v.u = ((unsigned)h) << 16; return v.f;
}

union HQ { u64 q[2]; bf16x8 v; };

// ---------------- prep kernels ----------------

__global__ __launch_bounds__(256) void k_cvt(const float* __restrict__ x,
                                             unsigned short* __restrict__ o, int n) {
  int i = (blockIdx.x * 256 + threadIdx.x) * 8;
  if (i >= n) return;
  float4 a = *(const float4*)(x + i), b = *(const float4*)(x + i + 4);
  uint4 u;
  u.x = (unsigned)f2b(a.x) | ((unsigned)f2b(a.y) << 16);
  u.y = (unsigned)f2b(a.z) | ((unsigned)f2b(a.w) << 16);
  u.z = (unsigned)f2b(b.x) | ((unsigned)f2b(b.y) << 16);
  u.w = (unsigned)f2b(b.z) | ((unsigned)f2b(b.w) << 16);
  *(uint4*)(o + i) = u;
}

__global__ __launch_bounds__(256) void k_cvt_wa(const float* __restrict__ Wih,
                                                unsigned short* __restrict__ Wa) {
  int u = blockIdx.x * 256 + threadIdx.x;
  int g = u >> 6, d = (u & 63) * 8;
  const float* p = Wih + (size_t)g * DC + d;
  float4 a = *(const float4*)p, b = *(const float4*)(p + 4);
  uint4 o;
  o.x = (unsigned)f2b(a.x) | ((unsigned)f2b(a.y) << 16);
  o.y = (unsigned)f2b(a.z) | ((unsigned)f2b(a.w) << 16);
  o.z = (unsigned)f2b(b.x) | ((unsigned)f2b(b.y) << 16);
  o.w = (unsigned)f2b(b.z) | ((unsigned)f2b(b.w) << 16);
  *(uint4*)(Wa + (size_t)g * Dd + d) = o;
}

__global__ __launch_bounds__(256) void k_cvt_wct(const float* __restrict__ Wih,
                                                 unsigned short* __restrict__ WcT) {
  int g = blockIdx.x * 256 + threadIdx.x;
  int c = blockIdx.y;
  WcT[(size_t)c * G3 + g] = f2b(Wih[(size_t)g * DC + Dd + c]);
}

__global__ __launch_bounds__(256) void k_pid(const float* __restrict__ ts,
                                             int* __restrict__ pid) {
  int bt = blockIdx.x * 256 + threadIdx.x;
  int t = bt & (Tt - 1);
  if (t == 0) { pid[bt] = -1; return; }
  const float* p = ts + (size_t)(bt - 1) * Cc;
  int id = 0;
  for (int c = 0; c < Cc; c += 4) {
    float4 v = *(const float4*)(p + c);
    if (v.x > 0.5f) id = c;
    if (v.y > 0.5f) id = c + 1;
    if (v.z > 0.5f) id = c + 2;
    if (v.w > 0.5f) id = c + 3;
  }
  pid[bt] = id;
}

__global__ __launch_bounds__(256) void k_cvtx(const float* __restrict__ gru,
                                              unsigned short* __restrict__ Xc, int t0) {
  int u = (blockIdx.x * 256 + threadIdx.x) * 8;
  int m = u >> 9, d = u & 511;
  int b = m >> 5, tl = m & 31;
  const float* p = gru + ((size_t)(b * Tt + t0 + tl)) * Dd + d;
  float4 a = *(const float4*)p, c = *(const float4*)(p + 4);
  uint4 o;
  o.x = (unsigned)f2b(a.x) | ((unsigned)f2b(a.y) << 16);
  o.y = (unsigned)f2b(a.z) | ((unsigned)f2b(a.w) << 16);
  o.z = (unsigned)f2b(c.x) | ((unsigned)f2b(c.y) << 16);
  o.w = (unsigned)f2b(c.z) | ((unsigned)f2b(c.w) << 16);
  *(uint4*)(Xc + (size_t)m * Dd + d) = o;
}

// ---------------- gates GEMM (per chunk, M=8192) ----------------
__global__ __launch_bounds__(256) void k_gates(const unsigned short* __restrict__ Xc,
                                               const unsigned short* __restrict__ Wa,
                                               const unsigned short* __restrict__ WcT,
                                               const float* __restrict__ bih,
                                               const int* __restrict__ pid,
                                               unsigned short* __restrict__ gx, int t0) {
  int m0 = blockIdx.x * 128, n0 = blockIdx.y * 128;
  int l = threadIdx.x & 63, w = threadIdx.x >> 6;
  int wm = w >> 1, wn = w & 1;
  int r0 = m0 + 64 * wm, c0 = n0 + 64 * wn;
  int lr = l & 15, lk = (l >> 4) * 8;
  f32x4 acc[4][4] = {};
  for (int kk = 0; kk < 16; ++kk) {
    int k = kk * 32 + lk;
    bf16x8 a[4], b[4];
#pragma unroll
    for (int mf = 0; mf < 4; ++mf)
      a[mf] = *(const bf16x8*)(Xc + (size_t)(r0 + 16 * mf + lr) * Dd + k);
#pragma unroll
    for (int nf = 0; nf < 4; ++nf)
      b[nf] = *(const bf16x8*)(Wa + (size_t)(c0 + 16 * nf + lr) * Dd + k);
#pragma unroll
    for (int mf = 0; mf < 4; ++mf)
#pragma unroll
      for (int nf = 0; nf < 4; ++nf)
        acc[mf][nf] = __builtin_amdgcn_mfma_f32_16x16x32_bf16(a[mf], b[nf], acc[mf][nf], 0, 0, 0);
  }
  int ri = (l >> 4) * 4;
  for (int mf = 0; mf < 4; ++mf) {
    int rowb = r0 + 16 * mf + ri;
    int pd[4];
#pragma unroll
    for (int i = 0; i < 4; ++i) {
      int rr = rowb + i;
      pd[i] = pid[(size_t)(rr >> 5) * Tt + t0 + (rr & 31)];
    }
    for (int nf = 0; nf < 4; ++nf) {
      int g = c0 + 16 * nf + lr;
      float bi = bih[g];
#pragma unroll
      for (int i = 0; i < 4; ++i) {
        float v = acc[mf][nf][i] + bi;
        if (pd[i] >= 0) v += b2f(WcT[(size_t)pd[i] * G3 + g]);
        gx[(size_t)(rowb + i) * G3 + g] = f2b(v);
      }
    }
  }
}

// ---------------- recurrent scan chunk (plain launch, group sync) ----------------
// 256 blocks x 256 threads. xcd=bid&7, slot=bid>>3, mg=xcd>>1 (rows [64mg,+64)),
// nb=slot*2+(xcd&1) (hcols [16nb,+16)). Wave w: K-slice [256w,+256).
// Sync group = 64 blocks sharing mg; cnt[mg][t] target 64.
// ALL h traffic via AGENT-scope atomics (MALL-coherent).
__global__ __launch_bounds__(256, 1) void k_scan(const unsigned short* __restrict__ Whh,
                                                 const float* __restrict__ bhh,
                                                 const unsigned short* __restrict__ gx,
                                                 u64* __restrict__ hbq,
                                                 unsigned short* __restrict__ hsc,
                                                 unsigned int* __restrict__ cnt,
                                                 int t0) {
  __shared__ float red[4 * 64 * 52];  // [wave][row64][3*16 pad52] = 53.2KB
  const int tid = threadIdx.x;
  const int l = tid & 63, w = tid >> 6;
  const int bid = blockIdx.x;
  const int xcd = bid & 7, slot = bid >> 3;
  const int mg = xcd >> 1, nb = slot * 2 + (xcd & 1);
  const int lr = l & 15, lk = (l >> 4) * 8;
  const int hcolBase = 16 * nb;
  const int ri = (l >> 4) * 4;

  // resident W_hh fragments: 3 gates x 8 k-steps (rows {hcol, H+hcol, 2H+hcol})
  bf16x8 Breg[3][8];
#pragma unroll
  for (int nf = 0; nf < 3; ++nf) {
    int wrow = nf * Hh + hcolBase + lr;
#pragma unroll
    for (int kk = 0; kk < 8; ++kk) {
      int k = 256 * w + 32 * kk + lk;
      Breg[nf][kk] = *(const bf16x8*)(Whh + (size_t)wrow * Hh + k);
    }
  }

  // epilogue mapping: thread -> 1 row x 4 cols (8-byte h I/O)
  const int erow = tid >> 2, ej0 = (tid & 3) * 4;
  const int eb = 64 * mg + erow;
  const int ecol = hcolBase + ej0;
  const float4 bhr4 = *(const float4*)(bhh + ecol);
  const float4 bhz4 = *(const float4*)(bhh + Hh + ecol);
  const float4 bhn4 = *(const float4*)(bhh + 2 * Hh + ecol);

  for (int tl = 0; tl < TC; ++tl) {
    const int t = t0 + tl;
    const size_t pcur = (size_t)(t & 1) * (Bb * Hh / 4);
    const size_t pnxt = (size_t)((t & 1) ^ 1) * (Bb * Hh / 4);

    // prefetch gx for this step (produced by k_gates; safe pre-wait)
    const size_t gxo = (size_t)(eb * TC + tl) * G3;
    uint2 gr = *(const uint2*)(gx + gxo + ecol);
    uint2 gz = *(const uint2*)(gx + gxo + Hh + ecol);
    uint2 gn = *(const uint2*)(gx + gxo + 2 * Hh + ecol);

    // wait for the 64 blocks of this row-group to finish step t-1
    if (t > 0) {
      if (w == 0) {
        const unsigned int* cp = cnt + (mg << 8) + (t - 1);
        while (__hip_atomic_load(cp, __ATOMIC_RELAXED, __HIP_MEMORY_SCOPE_AGENT) < 64u)
          __builtin_amdgcn_s_sleep(1);
        __builtin_amdgcn_fence(__ATOMIC_ACQUIRE, "agent");
      }
      __syncthreads();
    }
    asm volatile("" ::: "memory");

    u64 hprev = __hip_atomic_load(hbq + pcur + (((size_t)eb << 10) + ecol) / 4,
                                  __ATOMIC_RELAXED, __HIP_MEMORY_SCOPE_AGENT);

    f32x4 acc[4][3] = {};
#pragma unroll
    for (int kk = 0; kk < 8; ++kk) {
      int k = 256 * w + 32 * kk + lk;
      bf16x8 a[4];
#pragma unroll
      for (int mf = 0; mf < 4; ++mf) {
        int row = 64 * mg + 16 * mf + lr;
        const u64* hp = hbq + pcur + (((size_t)row << 10) + k) / 4;
        HQ hq;
        hq.q[0] = __hip_atomic_load(hp, __ATOMIC_RELAXED, __HIP_MEMORY_SCOPE_AGENT);
        hq.q[1] = __hip_atomic_load(hp + 1, __ATOMIC_RELAXED, __HIP_MEMORY_SCOPE_AGENT);
        a[mf] = hq.v;
      }
#pragma unroll
      for (int mf = 0; mf < 4; ++mf)
#pragma unroll
        for (int nf = 0; nf < 3; ++nf)
          acc[mf][nf] = __builtin_amdgcn_mfma_f32_16x16x32_bf16(a[mf], Breg[nf][kk], acc[mf][nf], 0, 0, 0);
    }

    // partials -> LDS (cols: gate*16 + lr)
#pragma unroll
    for (int mf = 0; mf < 4; ++mf)
#pragma unroll
      for (int nf = 0; nf < 3; ++nf)
#pragma unroll
        for (int i = 0; i < 4; ++i)
          red[(w * 64 + 16 * mf + ri + i) * 52 + 16 * nf + lr] = acc[mf][nf][i];
    __syncthreads();

    // reduce 4 wave-partials + gate math, 1 row x 4 cols per thread
    f32x4 vr = {}, vz = {}, vn = {};
#pragma unroll
    for (int w2 = 0; w2 < 4; ++w2) {
      const float* rp = &red[(w2 * 64 + erow) * 52];
      vr += *(const f32x4*)(rp + ej0);
      vz += *(const f32x4*)(rp + 16 + ej0);
      vn += *(const f32x4*)(rp + 32 + ej0);
    }
    unsigned short grs[4] = {(unsigned short)gr.x, (unsigned short)(gr.x >> 16),
                             (unsigned short)gr.y, (unsigned short)(gr.y >> 16)};
    unsigned short gzs[4] = {(unsigned short)gz.x, (unsigned short)(gz.x >> 16),
                             (unsigned short)gz.y, (unsigned short)(gz.y >> 16)};
    unsigned short gns[4] = {(unsigned short)gn.x, (unsigned short)(gn.x >> 16),
                             (unsigned short)gn.y, (unsigned short)(gn.y >> 16)};
    u64 ho = 0;
#pragma unroll
    for (int i = 0; i < 4; ++i) {
      float hr = vr[i] + (&bhr4.x)[i];
      float hz = vz[i] + (&bhz4.x)[i];
      float hn = vn[i] + (&bhn4.x)[i];
      float xr = b2f(grs[i]), xz = b2f(gzs[i]), xn = b2f(gns[i]);
      float rg = 1.f / (1.f + __expf(-(xr + hr)));
      float zg = 1.f / (1.f + __expf(-(xz + hz)));
      float pre = xn + rg * hn;
      pre = fminf(fmaxf(pre, -15.f), 15.f);
      float e = __expf(-2.f * pre);
      float ng = (1.f - e) / (1.f + e);
      float hp = b2f((unsigned short)(hprev >> (16 * i)));
      float hv = (1.f - zg) * ng + zg * hp;
      ho |= (u64)f2b(hv) << (16 * i);
    }
    __hip_atomic_store(hbq + pnxt + (((size_t)eb << 10) + ecol) / 4, ho,
                       __ATOMIC_RELAXED, __HIP_MEMORY_SCOPE_AGENT);
    *(u64*)(hsc + (size_t)(eb * TC + tl) * Hh + ecol) = ho;

    asm volatile("s_waitcnt vmcnt(0)" ::: "memory");  // this wave's stores acked
    __syncthreads();  // all waves drained; also protects red[] reuse
    if (tid == 0)
      __hip_atomic_fetch_add(cnt + (mg << 8) + t, 1u,
                             __ATOMIC_RELEASE, __HIP_MEMORY_SCOPE_AGENT);
  }
}

// ---------------- logits GEMM (per chunk, M=8192) ----------------
__global__ __launch_bounds__(256) void k_logits(const unsigned short* __restrict__ hsc,
                                                const unsigned short* __restrict__ Wo,
                                                const float* __restrict__ bout,
                                                float* __restrict__ out, int t0) {
  int blk = blockIdx.x;
  int l = threadIdx.x & 63, w = threadIdx.x >> 6;
  int lr = l & 15, lk = (l >> 4) * 8;
  int r0 = blk * 64 + 16 * w;
  f32x4 acc[8] = {};
  for (int kk = 0; kk < 32; ++kk) {
    int k = kk * 32 + lk;
    bf16x8 a = *(const bf16x8*)(hsc + (size_t)(r0 + lr) * Hh + k);
#pragma unroll
    for (int nf = 0; nf < 8; ++nf) {
      bf16x8 b = *(const bf16x8*)(Wo + (size_t)(16 * nf + lr) * Hh + k);
      acc[nf] = __builtin_amdgcn_mfma_f32_16x16x32_bf16(a, b, acc[nf], 0, 0, 0);
    }
  }
  int ri = (l >> 4) * 4;
  for (int nf = 0; nf < 8; ++nf) {
    int c = 16 * nf + lr;
    float bo = bout[c];
#pragma unroll
    for (int i = 0; i < 4; ++i) {
      int m = r0 + ri + i;
      int grow = (m >> 5) * Tt + t0 + (m & 31);
      out[(size_t)grow * Cc + c] = acc[nf][i] + bo;
    }
  }
}

// ---------------- launch ----------------
extern "C" void kernel_launch(void* const* d_in, const int* in_sizes, int n_in,
                              void* d_out, int out_size, void* d_ws, size_t ws_size,
                              hipStream_t stream) {
  const float* gru = (const float*)d_in[0];
  const float* ts  = (const float*)d_in[1];
  const float* Wih = (const float*)d_in[2];
  const float* bih = (const float*)d_in[3];
  const float* Whh = (const float*)d_in[4];
  const float* bhh = (const float*)d_in[5];
  const float* Wou = (const float*)d_in[6];
  const float* bou = (const float*)d_in[7];

  char* ws = (char*)d_ws;
  size_t off = 0;
  auto alloc = [&](size_t bytes) -> void* {
    void* p = ws + off;
    off += (bytes + 255) & ~(size_t)255;
    return p;
  };
  unsigned short* Wa  = (unsigned short*)alloc((size_t)G3 * Dd * 2);
  unsigned short* WcT = (unsigned short*)alloc((size_t)Cc * G3 * 2);
  unsigned short* Whb = (unsigned short*)alloc((size_t)G3 * Hh * 2);
  unsigned short* Wob = (unsigned short*)alloc((size_t)Cc * Hh * 2);
  int*            pid = (int*)alloc((size_t)Bb * Tt * 4);
  u64*            hbq = (u64*)alloc((size_t)2 * Bb * Hh * 2);
  unsigned int*   cnt = (unsigned int*)alloc((size_t)4 * 256 * 4);
  unsigned short* Xc  = (unsigned short*)alloc((size_t)Bb * TC * Dd * 2);
  unsigned short* gx  = (unsigned short*)alloc((size_t)Bb * TC * G3 * 2);
  unsigned short* hsc = (unsigned short*)alloc((size_t)Bb * TC * Hh * 2);
  if (ws_size < off) return;

  k_cvt<<<(G3 * Hh) / 2048, 256, 0, stream>>>(Whh, Whb, G3 * Hh);
  k_cvt<<<(Cc * Hh) / 2048, 256, 0, stream>>>(Wou, Wob, Cc * Hh);
  k_cvt_wa<<<(G3 * 64) / 256, 256, 0, stream>>>(Wih, Wa);
  k_cvt_wct<<<dim3(G3 / 256, Cc), 256, 0, stream>>>(Wih, WcT);
  k_pid<<<(Bb * Tt) / 256, 256, 0, stream>>>(ts, pid);
  hipMemsetAsync(hbq, 0, (size_t)2 * Bb * Hh * 2, stream);
  hipMemsetAsync(cnt, 0, (size_t)4 * 256 * 4, stream);

  for (int c = 0; c < NC; ++c) {
    int t0 = c * TC;
    k_cvtx<<<(Bb * TC * Dd) / 2048, 256, 0, stream>>>(gru, Xc, t0);
    k_gates<<<dim3((Bb * TC) / 128, G3 / 128), 256, 0, stream>>>(Xc, Wa, WcT, bih, pid, gx, t0);
    k_scan<<<dim3(256), dim3(256), 0, stream>>>(Whb, bhh, gx, hbq, hsc, cnt, t0);
    k_logits<<<(Bb * TC) / 64, 256, 0, stream>>>(hsc, Wob, bou, (float*)d_out, t0);
  }
}

// Round 6
// 4130.609 us; speedup vs baseline: 2.6696x; 1.5392x over previous
//
#include <hip/hip_runtime.h>

// TerminalGRU: B=256 T=256 D=512 H=1024 C=128
// Chunked pipeline (TC=32 steps x 8 chunks):
//   per chunk: k_cvtx -> k_gates (MFMA GEMM) -> k_scan (plain launch, 256 blocks,
//              group-scoped counter sync, MALL-coherent h exchange) -> k_logits
// Round-5 post-mortem: passed at 6.36ms; k_scan 637us/chunk dominated by the
// RELEASE fetch_add (buffer_wbl2 sc1 = full L2 writeback) + ACQUIRE fence
// (buffer_inv sc1) per block per step. But ALL h payload moves via AGENT-scope
// atomics (sc0 sc1 -> MALL, bypassing L1/L2), so there is nothing in L2 to
// flush/invalidate. This round: RELAXED counter add + no acquire fence.
// Ordering: producer vmcnt(0) (sc1 stores ack at coherence point) -> barrier ->
// relaxed add; consumer relaxed spin (branch resolves before h loads issue).

#define DEVI __device__ __forceinline__

typedef __bf16 bf16x8 __attribute__((ext_vector_type(8)));
typedef float f32x4 __attribute__((ext_vector_type(4)));
typedef unsigned long long u64;

static constexpr int Bb = 256, Tt = 256, Dd = 512, Hh = 1024, Cc = 128;
static constexpr int G3 = 3072, DC = 640, TC = 32, NC = Tt / TC;

DEVI unsigned short f2b(float f) {
  union { float f; unsigned u; } v; v.f = f;
  unsigned r = v.u + 0x7FFFu + ((v.u >> 16) & 1u);
  return (unsigned short)(r >> 16);
}
DEVI float b2f(unsigned short h) {
  union { unsigned u; float f; } v; v.u = ((unsigned)h) << 16; return v.f;
}

union HQ { u64 q[2]; bf16x8 v; };

// ---------------- prep kernels ----------------

__global__ __launch_bounds__(256) void k_cvt(const float* __restrict__ x,
                                             unsigned short* __restrict__ o, int n) {
  int i = (blockIdx.x * 256 + threadIdx.x) * 8;
  if (i >= n) return;
  float4 a = *(const float4*)(x + i), b = *(const float4*)(x + i + 4);
  uint4 u;
  u.x = (unsigned)f2b(a.x) | ((unsigned)f2b(a.y) << 16);
  u.y = (unsigned)f2b(a.z) | ((unsigned)f2b(a.w) << 16);
  u.z = (unsigned)f2b(b.x) | ((unsigned)f2b(b.y) << 16);
  u.w = (unsigned)f2b(b.z) | ((unsigned)f2b(b.w) << 16);
  *(uint4*)(o + i) = u;
}

__global__ __launch_bounds__(256) void k_cvt_wa(const float* __restrict__ Wih,
                                                unsigned short* __restrict__ Wa) {
  int u = blockIdx.x * 256 + threadIdx.x;
  int g = u >> 6, d = (u & 63) * 8;
  const float* p = Wih + (size_t)g * DC + d;
  float4 a = *(const float4*)p, b = *(const float4*)(p + 4);
  uint4 o;
  o.x = (unsigned)f2b(a.x) | ((unsigned)f2b(a.y) << 16);
  o.y = (unsigned)f2b(a.z) | ((unsigned)f2b(a.w) << 16);
  o.z = (unsigned)f2b(b.x) | ((unsigned)f2b(b.y) << 16);
  o.w = (unsigned)f2b(b.z) | ((unsigned)f2b(b.w) << 16);
  *(uint4*)(Wa + (size_t)g * Dd + d) = o;
}

__global__ __launch_bounds__(256) void k_cvt_wct(const float* __restrict__ Wih,
                                                 unsigned short* __restrict__ WcT) {
  int g = blockIdx.x * 256 + threadIdx.x;
  int c = blockIdx.y;
  WcT[(size_t)c * G3 + g] = f2b(Wih[(size_t)g * DC + Dd + c]);
}

__global__ __launch_bounds__(256) void k_pid(const float* __restrict__ ts,
                                             int* __restrict__ pid) {
  int bt = blockIdx.x * 256 + threadIdx.x;
  int t = bt & (Tt - 1);
  if (t == 0) { pid[bt] = -1; return; }
  const float* p = ts + (size_t)(bt - 1) * Cc;
  int id = 0;
  for (int c = 0; c < Cc; c += 4) {
    float4 v = *(const float4*)(p + c);
    if (v.x > 0.5f) id = c;
    if (v.y > 0.5f) id = c + 1;
    if (v.z > 0.5f) id = c + 2;
    if (v.w > 0.5f) id = c + 3;
  }
  pid[bt] = id;
}

__global__ __launch_bounds__(256) void k_cvtx(const float* __restrict__ gru,
                                              unsigned short* __restrict__ Xc, int t0) {
  int u = (blockIdx.x * 256 + threadIdx.x) * 8;
  int m = u >> 9, d = u & 511;
  int b = m >> 5, tl = m & 31;
  const float* p = gru + ((size_t)(b * Tt + t0 + tl)) * Dd + d;
  float4 a = *(const float4*)p, c = *(const float4*)(p + 4);
  uint4 o;
  o.x = (unsigned)f2b(a.x) | ((unsigned)f2b(a.y) << 16);
  o.y = (unsigned)f2b(a.z) | ((unsigned)f2b(a.w) << 16);
  o.z = (unsigned)f2b(c.x) | ((unsigned)f2b(c.y) << 16);
  o.w = (unsigned)f2b(c.z) | ((unsigned)f2b(c.w) << 16);
  *(uint4*)(Xc + (size_t)m * Dd + d) = o;
}

// ---------------- gates GEMM (per chunk, M=8192) ----------------
__global__ __launch_bounds__(256) void k_gates(const unsigned short* __restrict__ Xc,
                                               const unsigned short* __restrict__ Wa,
                                               const unsigned short* __restrict__ WcT,
                                               const float* __restrict__ bih,
                                               const int* __restrict__ pid,
                                               unsigned short* __restrict__ gx, int t0) {
  int m0 = blockIdx.x * 128, n0 = blockIdx.y * 128;
  int l = threadIdx.x & 63, w = threadIdx.x >> 6;
  int wm = w >> 1, wn = w & 1;
  int r0 = m0 + 64 * wm, c0 = n0 + 64 * wn;
  int lr = l & 15, lk = (l >> 4) * 8;
  f32x4 acc[4][4] = {};
  for (int kk = 0; kk < 16; ++kk) {
    int k = kk * 32 + lk;
    bf16x8 a[4], b[4];
#pragma unroll
    for (int mf = 0; mf < 4; ++mf)
      a[mf] = *(const bf16x8*)(Xc + (size_t)(r0 + 16 * mf + lr) * Dd + k);
#pragma unroll
    for (int nf = 0; nf < 4; ++nf)
      b[nf] = *(const bf16x8*)(Wa + (size_t)(c0 + 16 * nf + lr) * Dd + k);
#pragma unroll
    for (int mf = 0; mf < 4; ++mf)
#pragma unroll
      for (int nf = 0; nf < 4; ++nf)
        acc[mf][nf] = __builtin_amdgcn_mfma_f32_16x16x32_bf16(a[mf], b[nf], acc[mf][nf], 0, 0, 0);
  }
  int ri = (l >> 4) * 4;
  for (int mf = 0; mf < 4; ++mf) {
    int rowb = r0 + 16 * mf + ri;
    int pd[4];
#pragma unroll
    for (int i = 0; i < 4; ++i) {
      int rr = rowb + i;
      pd[i] = pid[(size_t)(rr >> 5) * Tt + t0 + (rr & 31)];
    }
    for (int nf = 0; nf < 4; ++nf) {
      int g = c0 + 16 * nf + lr;
      float bi = bih[g];
#pragma unroll
      for (int i = 0; i < 4; ++i) {
        float v = acc[mf][nf][i] + bi;
        if (pd[i] >= 0) v += b2f(WcT[(size_t)pd[i] * G3 + g]);
        gx[(size_t)(rowb + i) * G3 + g] = f2b(v);
      }
    }
  }
}

// ---------------- recurrent scan chunk (plain launch, group sync) ----------------
// 256 blocks x 256 threads. xcd=bid&7, slot=bid>>3, mg=xcd>>1 (rows [64mg,+64)),
// nb=slot*2+(xcd&1) (hcols [16nb,+16)). Wave w: K-slice [256w,+256).
// Sync group = 64 blocks sharing mg; cnt[mg][t] target 64.
// ALL h traffic via AGENT-scope atomics (MALL-coherent); counters RELAXED --
// no wbl2/inv (nothing lives in L1/L2 to flush).
__global__ __launch_bounds__(256, 1) void k_scan(const unsigned short* __restrict__ Whh,
                                                 const float* __restrict__ bhh,
                                                 const unsigned short* __restrict__ gx,
                                                 u64* __restrict__ hbq,
                                                 unsigned short* __restrict__ hsc,
                                                 unsigned int* __restrict__ cnt,
                                                 int t0) {
  __shared__ float red[4 * 64 * 52];  // [wave][row64][3*16 pad52] = 53.2KB
  const int tid = threadIdx.x;
  const int l = tid & 63, w = tid >> 6;
  const int bid = blockIdx.x;
  const int xcd = bid & 7, slot = bid >> 3;
  const int mg = xcd >> 1, nb = slot * 2 + (xcd & 1);
  const int lr = l & 15, lk = (l >> 4) * 8;
  const int hcolBase = 16 * nb;
  const int ri = (l >> 4) * 4;

  // resident W_hh fragments: 3 gates x 8 k-steps (rows {hcol, H+hcol, 2H+hcol})
  bf16x8 Breg[3][8];
#pragma unroll
  for (int nf = 0; nf < 3; ++nf) {
    int wrow = nf * Hh + hcolBase + lr;
#pragma unroll
    for (int kk = 0; kk < 8; ++kk) {
      int k = 256 * w + 32 * kk + lk;
      Breg[nf][kk] = *(const bf16x8*)(Whh + (size_t)wrow * Hh + k);
    }
  }

  // epilogue mapping: thread -> 1 row x 4 cols (8-byte h I/O)
  const int erow = tid >> 2, ej0 = (tid & 3) * 4;
  const int eb = 64 * mg + erow;
  const int ecol = hcolBase + ej0;
  const float4 bhr4 = *(const float4*)(bhh + ecol);
  const float4 bhz4 = *(const float4*)(bhh + Hh + ecol);
  const float4 bhn4 = *(const float4*)(bhh + 2 * Hh + ecol);

  for (int tl = 0; tl < TC; ++tl) {
    const int t = t0 + tl;
    const size_t pcur = (size_t)(t & 1) * (Bb * Hh / 4);
    const size_t pnxt = (size_t)((t & 1) ^ 1) * (Bb * Hh / 4);

    // prefetch gx for this step (produced by k_gates; safe pre-wait)
    const size_t gxo = (size_t)(eb * TC + tl) * G3;
    uint2 gr = *(const uint2*)(gx + gxo + ecol);
    uint2 gz = *(const uint2*)(gx + gxo + Hh + ecol);
    uint2 gn = *(const uint2*)(gx + gxo + 2 * Hh + ecol);

    // wait for the 64 blocks of this row-group to finish step t-1
    if (t > 0) {
      if (w == 0) {
        const unsigned int* cp = cnt + (mg << 8) + (t - 1);
        while (__hip_atomic_load(cp, __ATOMIC_RELAXED, __HIP_MEMORY_SCOPE_AGENT) < 64u)
          __builtin_amdgcn_s_sleep(1);
      }
      __syncthreads();
    }
    asm volatile("" ::: "memory");

    u64 hprev = __hip_atomic_load(hbq + pcur + (((size_t)eb << 10) + ecol) / 4,
                                  __ATOMIC_RELAXED, __HIP_MEMORY_SCOPE_AGENT);

    f32x4 acc[4][3] = {};
#pragma unroll
    for (int kk = 0; kk < 8; ++kk) {
      int k = 256 * w + 32 * kk + lk;
      bf16x8 a[4];
#pragma unroll
      for (int mf = 0; mf < 4; ++mf) {
        int row = 64 * mg + 16 * mf + lr;
        const u64* hp = hbq + pcur + (((size_t)row << 10) + k) / 4;
        HQ hq;
        hq.q[0] = __hip_atomic_load(hp, __ATOMIC_RELAXED, __HIP_MEMORY_SCOPE_AGENT);
        hq.q[1] = __hip_atomic_load(hp + 1, __ATOMIC_RELAXED, __HIP_MEMORY_SCOPE_AGENT);
        a[mf] = hq.v;
      }
#pragma unroll
      for (int mf = 0; mf < 4; ++mf)
#pragma unroll
        for (int nf = 0; nf < 3; ++nf)
          acc[mf][nf] = __builtin_amdgcn_mfma_f32_16x16x32_bf16(a[mf], Breg[nf][kk], acc[mf][nf], 0, 0, 0);
    }

    // partials -> LDS (cols: gate*16 + lr)
#pragma unroll
    for (int mf = 0; mf < 4; ++mf)
#pragma unroll
      for (int nf = 0; nf < 3; ++nf)
#pragma unroll
        for (int i = 0; i < 4; ++i)
          red[(w * 64 + 16 * mf + ri + i) * 52 + 16 * nf + lr] = acc[mf][nf][i];
    __syncthreads();

    // reduce 4 wave-partials + gate math, 1 row x 4 cols per thread
    f32x4 vr = {}, vz = {}, vn = {};
#pragma unroll
    for (int w2 = 0; w2 < 4; ++w2) {
      const float* rp = &red[(w2 * 64 + erow) * 52];
      vr += *(const f32x4*)(rp + ej0);
      vz += *(const f32x4*)(rp + 16 + ej0);
      vn += *(const f32x4*)(rp + 32 + ej0);
    }
    unsigned short grs[4] = {(unsigned short)gr.x, (unsigned short)(gr.x >> 16),
                             (unsigned short)gr.y, (unsigned short)(gr.y >> 16)};
    unsigned short gzs[4] = {(unsigned short)gz.x, (unsigned short)(gz.x >> 16),
                             (unsigned short)gz.y, (unsigned short)(gz.y >> 16)};
    unsigned short gns[4] = {(unsigned short)gn.x, (unsigned short)(gn.x >> 16),
                             (unsigned short)gn.y, (unsigned short)(gn.y >> 16)};
    u64 ho = 0;
#pragma unroll
    for (int i = 0; i < 4; ++i) {
      float hr = vr[i] + (&bhr4.x)[i];
      float hz = vz[i] + (&bhz4.x)[i];
      float hn = vn[i] + (&bhn4.x)[i];
      float xr = b2f(grs[i]), xz = b2f(gzs[i]), xn = b2f(gns[i]);
      float rg = 1.f / (1.f + __expf(-(xr + hr)));
      float zg = 1.f / (1.f + __expf(-(xz + hz)));
      float pre = xn + rg * hn;
      pre = fminf(fmaxf(pre, -15.f), 15.f);
      float e = __expf(-2.f * pre);
      float ng = (1.f - e) / (1.f + e);
      float hp = b2f((unsigned short)(hprev >> (16 * i)));
      float hv = (1.f - zg) * ng + zg * hp;
      ho |= (u64)f2b(hv) << (16 * i);
    }
    __hip_atomic_store(hbq + pnxt + (((size_t)eb << 10) + ecol) / 4, ho,
                       __ATOMIC_RELAXED, __HIP_MEMORY_SCOPE_AGENT);
    *(u64*)(hsc + (size_t)(eb * TC + tl) * Hh + ecol) = ho;

    asm volatile("s_waitcnt vmcnt(0)" ::: "memory");  // sc1 stores acked at MALL
    __syncthreads();  // all waves drained; also protects red[] reuse
    if (tid == 0)
      __hip_atomic_fetch_add(cnt + (mg << 8) + t, 1u,
                             __ATOMIC_RELAXED, __HIP_MEMORY_SCOPE_AGENT);
  }
}

// ---------------- logits GEMM (per chunk, M=8192) ----------------
__global__ __launch_bounds__(256) void k_logits(const unsigned short* __restrict__ hsc,
                                                const unsigned short* __restrict__ Wo,
                                                const float* __restrict__ bout,
                                                float* __restrict__ out, int t0) {
  int blk = blockIdx.x;
  int l = threadIdx.x & 63, w = threadIdx.x >> 6;
  int lr = l & 15, lk = (l >> 4) * 8;
  int r0 = blk * 64 + 16 * w;
  f32x4 acc[8] = {};
  for (int kk = 0; kk < 32; ++kk) {
    int k = kk * 32 + lk;
    bf16x8 a = *(const bf16x8*)(hsc + (size_t)(r0 + lr) * Hh + k);
#pragma unroll
    for (int nf = 0; nf < 8; ++nf) {
      bf16x8 b = *(const bf16x8*)(Wo + (size_t)(16 * nf + lr) * Hh + k);
      acc[nf] = __builtin_amdgcn_mfma_f32_16x16x32_bf16(a, b, acc[nf], 0, 0, 0);
    }
  }
  int ri = (l >> 4) * 4;
  for (int nf = 0; nf < 8; ++nf) {
    int c = 16 * nf + lr;
    float bo = bout[c];
#pragma unroll
    for (int i = 0; i < 4; ++i) {
      int m = r0 + ri + i;
      int grow = (m >> 5) * Tt + t0 + (m & 31);
      out[(size_t)grow * Cc + c] = acc[nf][i] + bo;
    }
  }
}

// ---------------- launch ----------------
extern "C" void kernel_launch(void* const* d_in, const int* in_sizes, int n_in,
                              void* d_out, int out_size, void* d_ws, size_t ws_size,
                              hipStream_t stream) {
  const float* gru = (const float*)d_in[0];
  const float* ts  = (const float*)d_in[1];
  const float* Wih = (const float*)d_in[2];
  const float* bih = (const float*)d_in[3];
  const float* Whh = (const float*)d_in[4];
  const float* bhh = (const float*)d_in[5];
  const float* Wou = (const float*)d_in[6];
  const float* bou = (const float*)d_in[7];

  char* ws = (char*)d_ws;
  size_t off = 0;
  auto alloc = [&](size_t bytes) -> void* {
    void* p = ws + off;
    off += (bytes + 255) & ~(size_t)255;
    return p;
  };
  unsigned short* Wa  = (unsigned short*)alloc((size_t)G3 * Dd * 2);
  unsigned short* WcT = (unsigned short*)alloc((size_t)Cc * G3 * 2);
  unsigned short* Whb = (unsigned short*)alloc((size_t)G3 * Hh * 2);
  unsigned short* Wob = (unsigned short*)alloc((size_t)Cc * Hh * 2);
  int*            pid = (int*)alloc((size_t)Bb * Tt * 4);
  u64*            hbq = (u64*)alloc((size_t)2 * Bb * Hh * 2);
  unsigned int*   cnt = (unsigned int*)alloc((size_t)4 * 256 * 4);
  unsigned short* Xc  = (unsigned short*)alloc((size_t)Bb * TC * Dd * 2);
  unsigned short* gx  = (unsigned short*)alloc((size_t)Bb * TC * G3 * 2);
  unsigned short* hsc = (unsigned short*)alloc((size_t)Bb * TC * Hh * 2);
  if (ws_size < off) return;

  k_cvt<<<(G3 * Hh) / 2048, 256, 0, stream>>>(Whh, Whb, G3 * Hh);
  k_cvt<<<(Cc * Hh) / 2048, 256, 0, stream>>>(Wou, Wob, Cc * Hh);
  k_cvt_wa<<<(G3 * 64) / 256, 256, 0, stream>>>(Wih, Wa);
  k_cvt_wct<<<dim3(G3 / 256, Cc), 256, 0, stream>>>(Wih, WcT);
  k_pid<<<(Bb * Tt) / 256, 256, 0, stream>>>(ts, pid);
  hipMemsetAsync(hbq, 0, (size_t)2 * Bb * Hh * 2, stream);
  hipMemsetAsync(cnt, 0, (size_t)4 * 256 * 4, stream);

  for (int c = 0; c < NC; ++c) {
    int t0 = c * TC;
    k_cvtx<<<(Bb * TC * Dd) / 2048, 256, 0, stream>>>(gru, Xc, t0);
    k_gates<<<dim3((Bb * TC) / 128, G3 / 128), 256, 0, stream>>>(Xc, Wa, WcT, bih, pid, gx, t0);
    k_scan<<<dim3(256), dim3(256), 0, stream>>>(Whb, bhh, gx, hbq, hsc, cnt, t0);
    k_logits<<<(Bb * TC) / 64, 256, 0, stream>>>(hsc, Wob, bou, (float*)d_out, t0);
  }
}

// Round 7
// 3184.446 us; speedup vs baseline: 3.4628x; 1.2971x over previous
//
#include <hip/hip_runtime.h>

// TerminalGRU: B=256 T=256 D=512 H=1024 C=128
// Chunked pipeline (TC=32 steps x 8 chunks):
//   per chunk: k_cvtx -> k_gates (MFMA GEMM) -> k_scan (plain launch, 256 blocks,
//              group counter sync, ring-buffered h) -> k_logits
// Round-6 post-mortem: 351us/chunk scan; h reads were uncached 8B MALL atomics
// (32MB/step re-read, no L2 reuse). This round: h state in a 33-slot ring
// (slot = global step % 33) -> no address reuse within a launch -> consumer
// reads are PLAIN CACHED bf16x8 loads (stale lines impossible: first touch of
// each slot is after production; launch-start invalidate covers cross-launch
// reuse, proven by gx reuse since round 2). Producers still store h via 8B
// agent-scope atomics (MALL-visible before the relaxed counter bump).
// XCD swizzle: all 32 blocks/XCD share one row-group -> each h line fetched
// from MALL once per XCD then L2-hit.

#define DEVI __device__ __forceinline__

typedef __bf16 bf16x8 __attribute__((ext_vector_type(8)));
typedef float f32x4 __attribute__((ext_vector_type(4)));
typedef unsigned long long u64;

static constexpr int Bb = 256, Tt = 256, Dd = 512, Hh = 1024, Cc = 128;
static constexpr int G3 = 3072, DC = 640, TC = 32, NC = Tt / TC;
static constexpr int SLOTS = TC + 1;  // 33-slot h ring

DEVI unsigned short f2b(float f) {
  union { float f; unsigned u; } v; v.f = f;
  unsigned r = v.u + 0x7FFFu + ((v.u >> 16) & 1u);
  return (unsigned short)(r >> 16);
}
DEVI float b2f(unsigned short h) {
  union { unsigned u; float f; } v; v.u = ((unsigned)h) << 16; return v.f;
}

// ---------------- prep kernels ----------------

__global__ __launch_bounds__(256) void k_cvt(const float* __restrict__ x,
                                             unsigned short* __restrict__ o, int n) {
  int i = (blockIdx.x * 256 + threadIdx.x) * 8;
  if (i >= n) return;
  float4 a = *(const float4*)(x + i), b = *(const float4*)(x + i + 4);
  uint4 u;
  u.x = (unsigned)f2b(a.x) | ((unsigned)f2b(a.y) << 16);
  u.y = (unsigned)f2b(a.z) | ((unsigned)f2b(a.w) << 16);
  u.z = (unsigned)f2b(b.x) | ((unsigned)f2b(b.y) << 16);
  u.w = (unsigned)f2b(b.z) | ((unsigned)f2b(b.w) << 16);
  *(uint4*)(o + i) = u;
}

__global__ __launch_bounds__(256) void k_cvt_wa(const float* __restrict__ Wih,
                                                unsigned short* __restrict__ Wa) {
  int u = blockIdx.x * 256 + threadIdx.x;
  int g = u >> 6, d = (u & 63) * 8;
  const float* p = Wih + (size_t)g * DC + d;
  float4 a = *(const float4*)p, b = *(const float4*)(p + 4);
  uint4 o;
  o.x = (unsigned)f2b(a.x) | ((unsigned)f2b(a.y) << 16);
  o.y = (unsigned)f2b(a.z) | ((unsigned)f2b(a.w) << 16);
  o.z = (unsigned)f2b(b.x) | ((unsigned)f2b(b.y) << 16);
  o.w = (unsigned)f2b(b.z) | ((unsigned)f2b(b.w) << 16);
  *(uint4*)(Wa + (size_t)g * Dd + d) = o;
}

__global__ __launch_bounds__(256) void k_cvt_wct(const float* __restrict__ Wih,
                                                 unsigned short* __restrict__ WcT) {
  int g = blockIdx.x * 256 + threadIdx.x;
  int c = blockIdx.y;
  WcT[(size_t)c * G3 + g] = f2b(Wih[(size_t)g * DC + Dd + c]);
}

__global__ __launch_bounds__(256) void k_pid(const float* __restrict__ ts,
                                             int* __restrict__ pid) {
  int bt = blockIdx.x * 256 + threadIdx.x;
  int t = bt & (Tt - 1);
  if (t == 0) { pid[bt] = -1; return; }
  const float* p = ts + (size_t)(bt - 1) * Cc;
  int id = 0;
  for (int c = 0; c < Cc; c += 4) {
    float4 v = *(const float4*)(p + c);
    if (v.x > 0.5f) id = c;
    if (v.y > 0.5f) id = c + 1;
    if (v.z > 0.5f) id = c + 2;
    if (v.w > 0.5f) id = c + 3;
  }
  pid[bt] = id;
}

__global__ __launch_bounds__(256) void k_cvtx(const float* __restrict__ gru,
                                              unsigned short* __restrict__ Xc, int t0) {
  int u = (blockIdx.x * 256 + threadIdx.x) * 8;
  int m = u >> 9, d = u & 511;
  int b = m >> 5, tl = m & 31;
  const float* p = gru + ((size_t)(b * Tt + t0 + tl)) * Dd + d;
  float4 a = *(const float4*)p, c = *(const float4*)(p + 4);
  uint4 o;
  o.x = (unsigned)f2b(a.x) | ((unsigned)f2b(a.y) << 16);
  o.y = (unsigned)f2b(a.z) | ((unsigned)f2b(a.w) << 16);
  o.z = (unsigned)f2b(c.x) | ((unsigned)f2b(c.y) << 16);
  o.w = (unsigned)f2b(c.z) | ((unsigned)f2b(c.w) << 16);
  *(uint4*)(Xc + (size_t)m * Dd + d) = o;
}

// ---------------- gates GEMM (per chunk, M=8192) ----------------
__global__ __launch_bounds__(256) void k_gates(const unsigned short* __restrict__ Xc,
                                               const unsigned short* __restrict__ Wa,
                                               const unsigned short* __restrict__ WcT,
                                               const float* __restrict__ bih,
                                               const int* __restrict__ pid,
                                               unsigned short* __restrict__ gx, int t0) {
  int m0 = blockIdx.x * 128, n0 = blockIdx.y * 128;
  int l = threadIdx.x & 63, w = threadIdx.x >> 6;
  int wm = w >> 1, wn = w & 1;
  int r0 = m0 + 64 * wm, c0 = n0 + 64 * wn;
  int lr = l & 15, lk = (l >> 4) * 8;
  f32x4 acc[4][4] = {};
  for (int kk = 0; kk < 16; ++kk) {
    int k = kk * 32 + lk;
    bf16x8 a[4], b[4];
#pragma unroll
    for (int mf = 0; mf < 4; ++mf)
      a[mf] = *(const bf16x8*)(Xc + (size_t)(r0 + 16 * mf + lr) * Dd + k);
#pragma unroll
    for (int nf = 0; nf < 4; ++nf)
      b[nf] = *(const bf16x8*)(Wa + (size_t)(c0 + 16 * nf + lr) * Dd + k);
#pragma unroll
    for (int mf = 0; mf < 4; ++mf)
#pragma unroll
      for (int nf = 0; nf < 4; ++nf)
        acc[mf][nf] = __builtin_amdgcn_mfma_f32_16x16x32_bf16(a[mf], b[nf], acc[mf][nf], 0, 0, 0);
  }
  int ri = (l >> 4) * 4;
  for (int mf = 0; mf < 4; ++mf) {
    int rowb = r0 + 16 * mf + ri;
    int pd[4];
#pragma unroll
    for (int i = 0; i < 4; ++i) {
      int rr = rowb + i;
      pd[i] = pid[(size_t)(rr >> 5) * Tt + t0 + (rr & 31)];
    }
    for (int nf = 0; nf < 4; ++nf) {
      int g = c0 + 16 * nf + lr;
      float bi = bih[g];
#pragma unroll
      for (int i = 0; i < 4; ++i) {
        float v = acc[mf][nf][i] + bi;
        if (pd[i] >= 0) v += b2f(WcT[(size_t)pd[i] * G3 + g]);
        gx[(size_t)(rowb + i) * G3 + g] = f2b(v);
      }
    }
  }
}

// ---------------- recurrent scan chunk (ring h, plain cached reads) ----------------
// 256 blocks x 256 threads. xcd=bid&7, slot=bid>>3, mg=xcd>>1 (rows [64mg,+64)),
// nb=slot*2+(xcd&1) (hcols [16nb,+16)). Wave w: K-slice [256w,+256).
// Sync group = 64 blocks sharing mg; cnt[mg][t] target 64.
__global__ __launch_bounds__(256, 1) void k_scan(const unsigned short* __restrict__ Whh,
                                                 const float* __restrict__ bhh,
                                                 const unsigned short* __restrict__ gx,
                                                 unsigned short* __restrict__ hring,
                                                 unsigned short* __restrict__ hsc,
                                                 unsigned int* __restrict__ cnt,
                                                 int t0) {
  __shared__ float red[4 * 64 * 52];  // [wave][row64][3*16 pad52] = 53.2KB
  const int tid = threadIdx.x;
  const int l = tid & 63, w = tid >> 6;
  const int bid = blockIdx.x;
  const int xcd = bid & 7, slot = bid >> 3;
  const int mg = xcd >> 1, nb = slot * 2 + (xcd & 1);
  const int lr = l & 15, lk = (l >> 4) * 8;
  const int hcolBase = 16 * nb;
  const int ri = (l >> 4) * 4;

  // resident W_hh fragments: 3 gates x 8 k-steps (rows {hcol, H+hcol, 2H+hcol})
  bf16x8 Breg[3][8];
#pragma unroll
  for (int nf = 0; nf < 3; ++nf) {
    int wrow = nf * Hh + hcolBase + lr;
#pragma unroll
    for (int kk = 0; kk < 8; ++kk) {
      int k = 256 * w + 32 * kk + lk;
      Breg[nf][kk] = *(const bf16x8*)(Whh + (size_t)wrow * Hh + k);
    }
  }

  // epilogue mapping: thread -> 1 row x 4 cols (8-byte h I/O)
  const int erow = tid >> 2, ej0 = (tid & 3) * 4;
  const int eb = 64 * mg + erow;
  const int ecol = hcolBase + ej0;
  const float4 bhr4 = *(const float4*)(bhh + ecol);
  const float4 bhz4 = *(const float4*)(bhh + Hh + ecol);
  const float4 bhn4 = *(const float4*)(bhh + 2 * Hh + ecol);

  for (int tl = 0; tl < TC; ++tl) {
    const int t = t0 + tl;
    const unsigned short* hcur = hring + (size_t)(t % SLOTS) * (Bb * Hh);
    u64* hnq = (u64*)hring + (size_t)((t + 1) % SLOTS) * (Bb * Hh / 4);

    // prefetch gx for this step (produced by k_gates; safe pre-wait)
    const size_t gxo = (size_t)(eb * TC + tl) * G3;
    uint2 gr = *(const uint2*)(gx + gxo + ecol);
    uint2 gz = *(const uint2*)(gx + gxo + Hh + ecol);
    uint2 gn = *(const uint2*)(gx + gxo + 2 * Hh + ecol);

    // wait for the 64 blocks of this row-group to finish step t-1
    if (t > 0) {
      if (w == 0) {
        const unsigned int* cp = cnt + (mg << 8) + (t - 1);
        while (__hip_atomic_load(cp, __ATOMIC_RELAXED, __HIP_MEMORY_SCOPE_AGENT) < 64u)
          __builtin_amdgcn_s_sleep(1);
      }
      __syncthreads();
    }
    asm volatile("" ::: "memory");

    // h inputs: PLAIN cached loads (slot address untouched before production)
    u64 hprev = *(const u64*)(hcur + (size_t)eb * Hh + ecol);

    f32x4 acc[4][3] = {};
#pragma unroll
    for (int kk = 0; kk < 8; ++kk) {
      int k = 256 * w + 32 * kk + lk;
      bf16x8 a[4];
#pragma unroll
      for (int mf = 0; mf < 4; ++mf)
        a[mf] = *(const bf16x8*)(hcur + (size_t)(64 * mg + 16 * mf + lr) * Hh + k);
#pragma unroll
      for (int mf = 0; mf < 4; ++mf)
#pragma unroll
        for (int nf = 0; nf < 3; ++nf)
          acc[mf][nf] = __builtin_amdgcn_mfma_f32_16x16x32_bf16(a[mf], Breg[nf][kk], acc[mf][nf], 0, 0, 0);
    }

    // partials -> LDS (cols: gate*16 + lr)
#pragma unroll
    for (int mf = 0; mf < 4; ++mf)
#pragma unroll
      for (int nf = 0; nf < 3; ++nf)
#pragma unroll
        for (int i = 0; i < 4; ++i)
          red[(w * 64 + 16 * mf + ri + i) * 52 + 16 * nf + lr] = acc[mf][nf][i];
    __syncthreads();

    // reduce 4 wave-partials + gate math, 1 row x 4 cols per thread
    f32x4 vr = {}, vz = {}, vn = {};
#pragma unroll
    for (int w2 = 0; w2 < 4; ++w2) {
      const float* rp = &red[(w2 * 64 + erow) * 52];
      vr += *(const f32x4*)(rp + ej0);
      vz += *(const f32x4*)(rp + 16 + ej0);
      vn += *(const f32x4*)(rp + 32 + ej0);
    }
    unsigned short grs[4] = {(unsigned short)gr.x, (unsigned short)(gr.x >> 16),
                             (unsigned short)gr.y, (unsigned short)(gr.y >> 16)};
    unsigned short gzs[4] = {(unsigned short)gz.x, (unsigned short)(gz.x >> 16),
                             (unsigned short)gz.y, (unsigned short)(gz.y >> 16)};
    unsigned short gns[4] = {(unsigned short)gn.x, (unsigned short)(gn.x >> 16),
                             (unsigned short)gn.y, (unsigned short)(gn.y >> 16)};
    u64 ho = 0;
#pragma unroll
    for (int i = 0; i < 4; ++i) {
      float hr = vr[i] + (&bhr4.x)[i];
      float hz = vz[i] + (&bhz4.x)[i];
      float hn = vn[i] + (&bhn4.x)[i];
      float xr = b2f(grs[i]), xz = b2f(gzs[i]), xn = b2f(gns[i]);
      float rg = 1.f / (1.f + __expf(-(xr + hr)));
      float zg = 1.f / (1.f + __expf(-(xz + hz)));
      float pre = xn + rg * hn;
      pre = fminf(fmaxf(pre, -15.f), 15.f);
      float e = __expf(-2.f * pre);
      float ng = (1.f - e) / (1.f + e);
      float hp = b2f((unsigned short)(hprev >> (16 * i)));
      float hv = (1.f - zg) * ng + zg * hp;
      ho |= (u64)f2b(hv) << (16 * i);
    }
    // h output: MALL-visible store (consumers' caches hold no copy of this line)
    __hip_atomic_store(hnq + ((size_t)eb * Hh + ecol) / 4, ho,
                       __ATOMIC_RELAXED, __HIP_MEMORY_SCOPE_AGENT);
    *(u64*)(hsc + (size_t)(eb * TC + tl) * Hh + ecol) = ho;

    asm volatile("s_waitcnt vmcnt(0)" ::: "memory");  // sc1 stores acked at MALL
    __syncthreads();  // all waves drained; also protects red[] reuse
    if (tid == 0)
      __hip_atomic_fetch_add(cnt + (mg << 8) + t, 1u,
                             __ATOMIC_RELAXED, __HIP_MEMORY_SCOPE_AGENT);
  }
}

// ---------------- logits GEMM (per chunk, M=8192) ----------------
__global__ __launch_bounds__(256) void k_logits(const unsigned short* __restrict__ hsc,
                                                const unsigned short* __restrict__ Wo,
                                                const float* __restrict__ bout,
                                                float* __restrict__ out, int t0) {
  int blk = blockIdx.x;
  int l = threadIdx.x & 63, w = threadIdx.x >> 6;
  int lr = l & 15, lk = (l >> 4) * 8;
  int r0 = blk * 64 + 16 * w;
  f32x4 acc[8] = {};
  for (int kk = 0; kk < 32; ++kk) {
    int k = kk * 32 + lk;
    bf16x8 a = *(const bf16x8*)(hsc + (size_t)(r0 + lr) * Hh + k);
#pragma unroll
    for (int nf = 0; nf < 8; ++nf) {
      bf16x8 b = *(const bf16x8*)(Wo + (size_t)(16 * nf + lr) * Hh + k);
      acc[nf] = __builtin_amdgcn_mfma_f32_16x16x32_bf16(a, b, acc[nf], 0, 0, 0);
    }
  }
  int ri = (l >> 4) * 4;
  for (int nf = 0; nf < 8; ++nf) {
    int c = 16 * nf + lr;
    float bo = bout[c];
#pragma unroll
    for (int i = 0; i < 4; ++i) {
      int m = r0 + ri + i;
      int grow = (m >> 5) * Tt + t0 + (m & 31);
      out[(size_t)grow * Cc + c] = acc[nf][i] + bo;
    }
  }
}

// ---------------- launch ----------------
extern "C" void kernel_launch(void* const* d_in, const int* in_sizes, int n_in,
                              void* d_out, int out_size, void* d_ws, size_t ws_size,
                              hipStream_t stream) {
  const float* gru = (const float*)d_in[0];
  const float* ts  = (const float*)d_in[1];
  const float* Wih = (const float*)d_in[2];
  const float* bih = (const float*)d_in[3];
  const float* Whh = (const float*)d_in[4];
  const float* bhh = (const float*)d_in[5];
  const float* Wou = (const float*)d_in[6];
  const float* bou = (const float*)d_in[7];

  char* ws = (char*)d_ws;
  size_t off = 0;
  auto alloc = [&](size_t bytes) -> void* {
    void* p = ws + off;
    off += (bytes + 255) & ~(size_t)255;
    return p;
  };
  unsigned short* Wa    = (unsigned short*)alloc((size_t)G3 * Dd * 2);
  unsigned short* WcT   = (unsigned short*)alloc((size_t)Cc * G3 * 2);
  unsigned short* Whb   = (unsigned short*)alloc((size_t)G3 * Hh * 2);
  unsigned short* Wob   = (unsigned short*)alloc((size_t)Cc * Hh * 2);
  int*            pid   = (int*)alloc((size_t)Bb * Tt * 4);
  unsigned short* hring = (unsigned short*)alloc((size_t)SLOTS * Bb * Hh * 2);  // 16.9MB
  unsigned int*   cnt   = (unsigned int*)alloc((size_t)4 * 256 * 4);
  unsigned short* Xc    = (unsigned short*)alloc((size_t)Bb * TC * Dd * 2);
  unsigned short* gx    = (unsigned short*)alloc((size_t)Bb * TC * G3 * 2);
  unsigned short* hsc   = (unsigned short*)alloc((size_t)Bb * TC * Hh * 2);
  if (ws_size < off) return;

  k_cvt<<<(G3 * Hh) / 2048, 256, 0, stream>>>(Whh, Whb, G3 * Hh);
  k_cvt<<<(Cc * Hh) / 2048, 256, 0, stream>>>(Wou, Wob, Cc * Hh);
  k_cvt_wa<<<(G3 * 64) / 256, 256, 0, stream>>>(Wih, Wa);
  k_cvt_wct<<<dim3(G3 / 256, Cc), 256, 0, stream>>>(Wih, WcT);
  k_pid<<<(Bb * Tt) / 256, 256, 0, stream>>>(ts, pid);
  hipMemsetAsync(hring, 0, (size_t)Bb * Hh * 2, stream);  // slot 0 = h(0) = 0
  hipMemsetAsync(cnt, 0, (size_t)4 * 256 * 4, stream);

  for (int c = 0; c < NC; ++c) {
    int t0 = c * TC;
    k_cvtx<<<(Bb * TC * Dd) / 2048, 256, 0, stream>>>(gru, Xc, t0);
    k_gates<<<dim3((Bb * TC) / 128, G3 / 128), 256, 0, stream>>>(Xc, Wa, WcT, bih, pid, gx, t0);
    k_scan<<<dim3(256), dim3(256), 0, stream>>>(Whb, bhh, gx, hring, hsc, cnt, t0);
    k_logits<<<(Bb * TC) / 64, 256, 0, stream>>>(hsc, Wob, bou, (float*)d_out, t0);
  }
}